// Round 4
// baseline (132.878 us; speedup 1.0000x reference)
//
#include <hip/hip_runtime.h>
#include <stdint.h>

#define HH 512
#define WW 512
#define WPR 8                 // u64 words per row (512 bits)
#define NWORDS (HH * WPR)     // 4096 words per image
#define NTHREADS 1024
#define WPT (NWORDS / NTHREADS) // 4
#define NB 16                 // batch
#define NMASK (2 * NB)        // 32 packed masks (16 pred + 16 true)

typedef unsigned long long u64;

__device__ __forceinline__ u64 ldw(const u64* M, int r, int c) {
    return (r < 0 || r >= HH || c < 0 || c >= WPR) ? 0ULL : M[r * WPR + c];
}

// One Zhang-Suen sub-step for word (r,c). Bit k = pixel col c*64+k.
__device__ __forceinline__ u64 zs_word(const u64* M, int r, int c, int step) {
    u64 nm = ldw(M, r - 1, c - 1), nc = ldw(M, r - 1, c), np = ldw(M, r - 1, c + 1);
    u64 cm = ldw(M, r,     c - 1), cc = ldw(M, r,     c), cp = ldw(M, r,     c + 1);
    u64 sm = ldw(M, r + 1, c - 1), sc = ldw(M, r + 1, c), sp = ldw(M, r + 1, c + 1);

    u64 P2 = nc;
    u64 P3 = (nc >> 1) | (np << 63);
    u64 P4 = (cc >> 1) | (cp << 63);
    u64 P5 = (sc >> 1) | (sp << 63);
    u64 P6 = sc;
    u64 P7 = (sc << 1) | (sm >> 63);
    u64 P8 = (cc << 1) | (cm >> 63);
    u64 P9 = (nc << 1) | (nm >> 63);

    u64 ab = P2 ^ P3;
    u64 s1 = ab ^ P4, c1 = (P2 & P3) | (ab & P4);
    u64 de = P5 ^ P6;
    u64 s2 = de ^ P7, c2 = (P5 & P6) | (de & P7);
    u64 s3 = P8 ^ P9, c3 = P8 & P9;
    u64 gh = s1 ^ s2;
    u64 b0 = gh ^ s3, c4 = (s1 & s2) | (gh & s3);
    u64 ij = c1 ^ c2;
    u64 s4 = ij ^ c3, c5 = (c1 & c2) | (ij & c3);
    u64 b1 = s4 ^ c4, c6 = s4 & c4;
    u64 b2 = c5 ^ c6, b3 = c5 & c6;

    u64 Bge2 = b1 | b2 | b3;
    u64 Ble6 = ~(b3 | (b2 & b1 & b0));

    u64 a1, a2, t;
    t = ~P2 & P3; a1 = t; a2 = 0ULL;
    t = ~P3 & P4; a2 |= a1 & t; a1 |= t;
    t = ~P4 & P5; a2 |= a1 & t; a1 |= t;
    t = ~P5 & P6; a2 |= a1 & t; a1 |= t;
    t = ~P6 & P7; a2 |= a1 & t; a1 |= t;
    t = ~P7 & P8; a2 |= a1 & t; a1 |= t;
    t = ~P8 & P9; a2 |= a1 & t; a1 |= t;
    t = ~P9 & P2; a2 |= a1 & t; a1 |= t;
    u64 Aeq1 = a1 & ~a2;

    u64 sccond;
    if (step == 0) sccond = ~(P2 & P4 & P6) & ~(P4 & P6 & P8);
    else           sccond = ~(P2 & P4 & P8) & ~(P2 & P6 & P8);

    return cc & ~(Bge2 & Ble6 & Aeq1 & sccond);
}

// ---------------- pack: full-chip binarize + bit-pack ----------------
// 512 blocks x 256 threads = 2048 waves; each wave packs 64 u64 words.
__global__ __launch_bounds__(256)
void pack_kernel(const float* __restrict__ y_pred,
                 const float* __restrict__ y_true,
                 u64* __restrict__ bits /* [32][NWORDS] */,
                 int* __restrict__ cnt /* [16][4] */) {
    if (blockIdx.x == 0 && threadIdx.x < 4 * NB) cnt[threadIdx.x] = 0;
    int gw = (blockIdx.x * 256 + threadIdx.x) >> 6;   // global wave id 0..2047
    int lane = threadIdx.x & 63;
    int wbase = gw * 64;
    #pragma unroll 4
    for (int it = 0; it < 64; ++it) {
        int wi = wbase + it;                          // word index 0..131071
        int img = wi >> 12;
        const float* src = (img < NB) ? y_pred + (size_t)img * (HH * WW)
                                      : y_true + (size_t)(img - NB) * (HH * WW);
        float v = src[((wi & (NWORDS - 1)) << 6) + lane];
        u64 w = __ballot(v > 0.5f);
        if (lane == 0) bits[wi] = w;
    }
}

// ---------------- skeletonize: one block per mask (32 blocks) ----------------
// Dirty tracking: Cp[r+1] bit (c+1) set iff word (r,c) changed in either of the
// last two sub-steps. need(word r,c) = bits c..c+2 of Cp[r]|Cp[r+1]|Cp[r+2].
__global__ __launch_bounds__(NTHREADS)
void skel_kernel(u64* __restrict__ bits /* [32][NWORDS], in-place */) {
    __shared__ u64 M[NWORDS];               // 32 KB
    __shared__ unsigned int Cp[HH + 2];     // padded row change masks
    __shared__ int s_any[2];

    int bx = blockIdx.x;
    int tid = threadIdx.x;
    int lane = tid & 63;
    u64* mine = bits + (size_t)bx * NWORDS;

    // load packed mask (32 KB, coalesced)
    #pragma unroll
    for (int k = 0; k < WPT; ++k) {
        int wi = k * NTHREADS + tid;
        M[wi] = mine[wi];
    }

    // init row masks: interior rows fully dirty (forces first two sub-steps)
    for (int i = tid; i < HH + 2; i += NTHREADS)
        Cp[i] = (i >= 1 && i <= HH) ? 0x1FEu : 0u;
    if (tid < 2) s_any[tid] = 0;

    unsigned dl[WPT];                       // row-owner's "last sub-step" mask
    #pragma unroll
    for (int k = 0; k < WPT; ++k) dl[k] = 0x1FEu;

    int p = 0;
    for (;;) {
        for (int step = 0; step < 2; ++step) {
            __syncthreads();                // load/init or prior writes visible
            u64 nv[WPT];
            u64 bal[WPT];
            bool anyc = false;
            #pragma unroll
            for (int k = 0; k < WPT; ++k) {
                int wi = k * NTHREADS + tid;
                int r = wi >> 3, c = wi & 7;
                unsigned need = ((Cp[r] | Cp[r + 1] | Cp[r + 2]) >> c) & 7u;
                bool chg = false;
                u64 x = 0;
                if (need) {
                    u64 cur = M[wi];
                    x = zs_word(M, r, c, step);
                    chg = (x != cur);
                }
                nv[k] = x;
                bal[k] = __ballot(chg);     // wave's 64 bits = 8 rows x 8 cols
                anyc |= (bal[k] != 0);
            }
            __syncthreads();                // all reads done before writes
            #pragma unroll
            for (int k = 0; k < WPT; ++k) {
                int wi = k * NTHREADS + tid;
                if ((bal[k] >> lane) & 1) M[wi] = nv[k];
                if ((lane & 7) == 0) {      // one owner lane per row
                    unsigned byte = ((unsigned)(bal[k] >> lane) & 0xFFu) << 1;
                    int idx = (wi >> 3) + 1;
                    Cp[idx] = byte | dl[k]; // union of last two sub-steps
                    dl[k] = byte;
                }
            }
            if (anyc) s_any[p] = 1;
        }
        __syncthreads();
        int done = (s_any[p] == 0);
        if (tid == 0) s_any[p ^ 1] = 0;
        p ^= 1;
        if (done) break;                    // uniform across block
    }

    // store skeleton back in place (coalesced)
    #pragma unroll
    for (int k = 0; k < WPT; ++k) {
        int wi = k * NTHREADS + tid;
        mine[wi] = M[wi];
    }
}

// ---------------- count: 16 strips/image, 256 blocks ----------------
#define STRIPS 16
#define SROWS (HH / STRIPS)   // 32 interior rows per strip
#define SR2 (SROWS + 6)       // + 3-row halo each side

__device__ __forceinline__ u64 ldws(const u64* M, int r, int c) {
    return (c < 0 || c >= WPR) ? 0ULL : M[r * WPR + c];   // rows always in range
}

// radius-3 disk dilation; strip-local r in [3, 3+SROWS)
__device__ __forceinline__ u64 dil3s(const u64* M, int r, int c) {
    u64 cm = ldws(M, r, c - 1), cc = ldws(M, r, c), cp = ldws(M, r, c + 1);
    u64 h = cc
          | (cc >> 1) | (cp << 63)
          | (cc >> 2) | (cp << 62)
          | (cc >> 3) | (cp << 61)
          | (cc << 1) | (cm >> 63)
          | (cc << 2) | (cm >> 62)
          | (cc << 3) | (cm >> 61);
    u64 um = ldws(M, r - 1, c - 1) | ldws(M, r + 1, c - 1) | ldws(M, r - 2, c - 1) | ldws(M, r + 2, c - 1);
    u64 uc = ldws(M, r - 1, c    ) | ldws(M, r + 1, c    ) | ldws(M, r - 2, c    ) | ldws(M, r + 2, c    );
    u64 up = ldws(M, r - 1, c + 1) | ldws(M, r + 1, c + 1) | ldws(M, r - 2, c + 1) | ldws(M, r + 2, c + 1);
    h |= uc
       | (uc >> 1) | (up << 63)
       | (uc >> 2) | (up << 62)
       | (uc << 1) | (um >> 63)
       | (uc << 2) | (um >> 62);
    h |= ldws(M, r - 3, c) | ldws(M, r + 3, c);
    return h;
}

__global__ __launch_bounds__(256)
void count_kernel(const u64* __restrict__ bits, int* __restrict__ cnt) {
    __shared__ u64 P[SR2 * WPR];
    __shared__ u64 G[SR2 * WPR];
    __shared__ int acc[4];

    int b = blockIdx.x / STRIPS;
    int s = blockIdx.x % STRIPS;
    int tid = threadIdx.x;
    int r0 = s * SROWS - 3;                 // global row of strip-local row 0

    const u64* sp = bits + (size_t)b * NWORDS;
    const u64* sg = bits + (size_t)(NB + b) * NWORDS;
    for (int i = tid; i < SR2 * WPR; i += 256) {
        int gr = r0 + (i >> 3);
        bool in = (gr >= 0 && gr < HH);
        int gi = gr * WPR + (i & 7);
        P[i] = in ? sp[gi] : 0ULL;
        G[i] = in ? sg[gi] : 0ULL;
    }
    if (tid < 4) acc[tid] = 0;
    __syncthreads();

    // one interior word per thread
    int r = (tid >> 3) + 3, c = tid & 7;
    u64 pw = P[r * WPR + c], gw = G[r * WPR + c];
    int cp  = __popcll(pw);
    int cg  = __popcll(gw);
    int tp  = __popcll(pw & dil3s(G, r, c));
    int fnh = __popcll(gw & dil3s(P, r, c));

    #pragma unroll
    for (int o = 32; o > 0; o >>= 1) {
        cp  += __shfl_down(cp, o);
        cg  += __shfl_down(cg, o);
        tp  += __shfl_down(tp, o);
        fnh += __shfl_down(fnh, o);
    }
    if ((tid & 63) == 0) {
        atomicAdd(&acc[0], cp);
        atomicAdd(&acc[1], cg);
        atomicAdd(&acc[2], tp);
        atomicAdd(&acc[3], fnh);
    }
    __syncthreads();
    if (tid < 4) atomicAdd(&cnt[b * 4 + tid], acc[tid]);
}

__global__ void ccq_reduce(const int* __restrict__ cnt, float* __restrict__ out) {
    int k = threadIdx.x;
    if (k < 3) {
        float s = 0.0f;
        for (int b = 0; b < NB; ++b) {
            float TP = (float)cnt[b * 4 + 2];
            float FP = (float)(cnt[b * 4 + 0] - cnt[b * 4 + 2]);
            float FN = (float)(cnt[b * 4 + 1] - cnt[b * 4 + 3]);
            float v = (k == 0) ? TP / (TP + FP + 1e-12f)
                    : (k == 1) ? TP / (TP + FN + 1e-12f)
                               : TP / (TP + FP + FN + 1e-12f);
            s += v;
        }
        out[k] = s * (1.0f / NB);
    }
}

extern "C" void kernel_launch(void* const* d_in, const int* in_sizes, int n_in,
                              void* d_out, int out_size, void* d_ws, size_t ws_size,
                              hipStream_t stream) {
    (void)in_sizes; (void)n_in; (void)out_size; (void)ws_size;
    const float* y_pred = (const float*)d_in[0];
    const float* y_true = (const float*)d_in[1];
    float* out = (float*)d_out;

    u64* bits = (u64*)d_ws;                               // 32 * 4096 * 8 = 1 MB
    int* cnt = (int*)((char*)d_ws + (size_t)NMASK * NWORDS * sizeof(u64)); // 64 ints

    hipLaunchKernelGGL(pack_kernel, dim3(512), dim3(256), 0, stream,
                       y_pred, y_true, bits, cnt);
    hipLaunchKernelGGL(skel_kernel, dim3(NMASK), dim3(NTHREADS), 0, stream, bits);
    hipLaunchKernelGGL(count_kernel, dim3(NB * STRIPS), dim3(256), 0, stream,
                       bits, cnt);
    hipLaunchKernelGGL(ccq_reduce, dim3(1), dim3(64), 0, stream, cnt, out);
}